// Round 4
// baseline (525.606 us; speedup 1.0000x reference)
//
#include <hip/hip_runtime.h>
#include <hip/hip_bf16.h>

// Problem constants
#define TB 128
#define TT 500
#define TS 200
#define TE 100
#define TH 100
#define NCLS 400              // 2*S  (one-hot width of x)
#define NG   400              // 4*H  (gate width)
#define BT   (TB*TT)          // 64000 (b,t) pairs

__device__ __forceinline__ float fsig(float x) { return 1.0f / (1.0f + __expf(-x)); }
__device__ __forceinline__ float ftanh(float x) { float e = __expf(2.0f * x); return 1.0f - 2.0f / (e + 1.0f); }

// ---------------------------------------------------------------------------
// Kernel A: compress one-hot x (B,T,400) -> idx2 and q (B,T,200) -> qi.
// One wave per (b,t).
// ---------------------------------------------------------------------------
__global__ void k_compress(const float* __restrict__ x, const float* __restrict__ q,
                           int* __restrict__ idx2, int* __restrict__ qi) {
  int gid  = blockIdx.x * blockDim.x + threadIdx.x;
  int wave = gid >> 6;
  int lane = threadIdx.x & 63;
  if (wave >= BT) return;

  const float4* xr = (const float4*)(x + (size_t)wave * NCLS);
  int li = -1;
  {
    float4 v = xr[lane];
    if (v.x > 0.5f) li = lane * 4 + 0;
    if (v.y > 0.5f) li = lane * 4 + 1;
    if (v.z > 0.5f) li = lane * 4 + 2;
    if (v.w > 0.5f) li = lane * 4 + 3;
    int ci = 64 + lane;
    if (ci < 100) {
      float4 w = xr[ci];
      if (w.x > 0.5f) li = ci * 4 + 0;
      if (w.y > 0.5f) li = ci * 4 + 1;
      if (w.z > 0.5f) li = ci * 4 + 2;
      if (w.w > 0.5f) li = ci * 4 + 3;
    }
  }
  #pragma unroll
  for (int off = 32; off; off >>= 1) li = max(li, __shfl_xor(li, off));

  const float4* qr = (const float4*)(q + (size_t)wave * TS);
  int qj = -1;
  if (lane < 50) {
    float4 v = qr[lane];
    if (v.x > 0.5f) qj = lane * 4 + 0;
    if (v.y > 0.5f) qj = lane * 4 + 1;
    if (v.z > 0.5f) qj = lane * 4 + 2;
    if (v.w > 0.5f) qj = lane * 4 + 3;
  }
  #pragma unroll
  for (int off = 32; off; off >>= 1) qj = max(qj, __shfl_xor(qj, off));

  if (lane == 0) { idx2[wave] = li; qi[wave] = qj; }
}

// ---------------------------------------------------------------------------
// Kernel B: precompute gather table G, base, count rows, Wo^T, R^T.
// ---------------------------------------------------------------------------
__global__ void k_precompute(const float* __restrict__ Wx, const float* __restrict__ bx,
                             const float* __restrict__ K, const float* __restrict__ lb,
                             const float* __restrict__ Wo, const float* __restrict__ R,
                             float* __restrict__ G, float* __restrict__ base,
                             float* __restrict__ crow0, float* __restrict__ crow1,
                             float* __restrict__ WoT, float* __restrict__ Rt) {
  int bid = blockIdx.x, tid = threadIdx.x;
  if (bid < NCLS) {
    if (tid < NG) {
      float acc = 0.0f;
      for (int e = 0; e < TE; ++e) acc = fmaf(Wx[bid * TE + e], K[e * NG + tid], acc);
      G[bid * NG + tid] = acc;
    }
  } else if (bid == NCLS) {
    if (tid < NG) {
      float acc = lb[tid];
      for (int e = 0; e < TE; ++e) acc = fmaf(bx[e], K[e * NG + tid], acc);
      base[tid]  = acc;
      crow0[tid] = K[100 * NG + tid] + K[102 * NG + tid];
      crow1[tid] = K[101 * NG + tid] + K[102 * NG + tid];
    }
  } else {
    int id = (bid - NCLS - 1) * 512 + tid;
    if (id < TS * TH) {
      int s = id / TH, k = id % TH;
      WoT[id] = Wo[k * TS + s];
    } else {
      int id2 = id - TS * TH;
      if (id2 < NG * TH) {
        int j = id2 / TH, k = id2 % TH;
        Rt[id2] = R[k * NG + j];          // Rt[j][k] = R[k][j]
      }
    }
  }
}

// ---------------------------------------------------------------------------
// Kernel C: LSTM recurrence. One block per batch b, 512 threads.
// Thread j<400 owns gate-column j of lstm_rk in 100 NAMED-VGPR floats
// (opaque-asm pinned so the compiler cannot sink them back to loads).
// __launch_bounds__(512, 1): we launch only 128 blocks on 256 CUs — exactly
// one workgroup per CU — so occupancy beyond the block's own 8 waves is
// worthless. min-waves=1 lifts the VGPR cap to 512 so the ~150-reg live set
// (100 fragment regs + working set) fits WITHOUT spilling to scratch.
// h broadcast from LDS. Thread 448 (wave 7, otherwise idle) runs the
// count-feature scan 2 steps ahead into a 4-slot LDS ring buffer.
// ---------------------------------------------------------------------------
#define OPQ4(v) asm("" : "+v"(v.x), "+v"(v.y), "+v"(v.z), "+v"(v.w))

__global__ void __launch_bounds__(512, 1) k_lstm(const int* __restrict__ idx2,
                                                 const float* __restrict__ G,
                                                 const float* __restrict__ base,
                                                 const float* __restrict__ crow0,
                                                 const float* __restrict__ crow1,
                                                 const float* __restrict__ Rt,
                                                 float* __restrict__ h_seq) {
  int b = blockIdx.x;
  int tid = threadIdx.x;

  __shared__ __align__(16) float h_s[TH];
  __shared__ float zs[NG];
  __shared__ float cnt[NCLS];
  __shared__ float2 ccic_ls[4];
  __shared__ int idx_ls[TT];

  for (int i = tid; i < TT; i += 512) idx_ls[i] = idx2[(size_t)b * TT + i];
  for (int i = tid; i < NCLS; i += 512) cnt[i] = 0.0f;
  if (tid < TH) h_s[tid] = 0.0f;
  float c_reg = 0.0f;

  int col = (tid < NG) ? tid : 0;
  const float4* rp = (const float4*)(Rt + (size_t)col * TH);
  float4 r0  = rp[0],  r1  = rp[1],  r2  = rp[2],  r3  = rp[3],  r4  = rp[4];
  float4 r5  = rp[5],  r6  = rp[6],  r7  = rp[7],  r8  = rp[8],  r9  = rp[9];
  float4 r10 = rp[10], r11 = rp[11], r12 = rp[12], r13 = rp[13], r14 = rp[14];
  float4 r15 = rp[15], r16 = rp[16], r17 = rp[17], r18 = rp[18], r19 = rp[19];
  float4 r20 = rp[20], r21 = rp[21], r22 = rp[22], r23 = rp[23], r24 = rp[24];
  OPQ4(r0);  OPQ4(r1);  OPQ4(r2);  OPQ4(r3);  OPQ4(r4);
  OPQ4(r5);  OPQ4(r6);  OPQ4(r7);  OPQ4(r8);  OPQ4(r9);
  OPQ4(r10); OPQ4(r11); OPQ4(r12); OPQ4(r13); OPQ4(r14);
  OPQ4(r15); OPQ4(r16); OPQ4(r17); OPQ4(r18); OPQ4(r19);
  OPQ4(r20); OPQ4(r21); OPQ4(r22); OPQ4(r23); OPQ4(r24);
  float basej = base[col], c0j = crow0[col], c1j = crow1[col];

  __syncthreads();               // idx_ls, cnt, h_s visible

  if (tid == 448) {              // seed count features for t = 0, 1
    #pragma unroll
    for (int tt = 0; tt < 2; ++tt) {
      int cls = idx_ls[tt];
      float n = cnt[cls] + 1.0f; cnt[cls] = n;
      float ns = cnt[cls ^ 1];
      float va = (cls & 1) ? ns : n;
      float vb = (cls & 1) ? n : ns;
      ccic_ls[tt] = make_float2(__logf(1.0f + va), __logf(1.0f + vb));
    }
  }
  float g_cur = G[(size_t)idx_ls[0] * NG + col];
  __syncthreads();               // ccic_ls[0..1] visible

  float* hout = h_seq + (size_t)b * TT * TH;

  for (int t = 0; t < TT; ++t) {
    // prefetch next step's G row (lands during this step's work)
    int tn1 = (t + 1 < TT) ? t + 1 : t;
    float g_next = G[(size_t)idx_ls[tn1] * NG + col];

    // wave 7: count scan, 2 steps ahead (off the critical path)
    if (tid == 448) {
      int tn = t + 2;
      if (tn < TT) {
        int cls = idx_ls[tn];
        float n = cnt[cls] + 1.0f; cnt[cls] = n;
        float ns = cnt[cls ^ 1];
        float va = (cls & 1) ? ns : n;
        float vb = (cls & 1) ? n : ns;
        ccic_ls[tn & 3] = make_float2(__logf(1.0f + va), __logf(1.0f + vb));
      }
    }

    if (tid < NG) {
      float2 cc = ccic_ls[t & 3];
      const float4* h4 = (const float4*)h_s;
      float a0 = 0.f, a1 = 0.f, a2 = 0.f, a3 = 0.f;
      #define FMASTEP(k) { float4 hv = h4[k]; \
        a0 = fmaf(hv.x, r##k.x, a0); a1 = fmaf(hv.y, r##k.y, a1); \
        a2 = fmaf(hv.z, r##k.z, a2); a3 = fmaf(hv.w, r##k.w, a3); }
      FMASTEP(0)  FMASTEP(1)  FMASTEP(2)  FMASTEP(3)  FMASTEP(4)
      FMASTEP(5)  FMASTEP(6)  FMASTEP(7)  FMASTEP(8)  FMASTEP(9)
      FMASTEP(10) FMASTEP(11) FMASTEP(12) FMASTEP(13) FMASTEP(14)
      FMASTEP(15) FMASTEP(16) FMASTEP(17) FMASTEP(18) FMASTEP(19)
      FMASTEP(20) FMASTEP(21) FMASTEP(22) FMASTEP(23) FMASTEP(24)
      #undef FMASTEP
      float z = basej + cc.x * c0j + cc.y * c1j + g_cur
              + ((a0 + a1) + (a2 + a3));
      // store ACTIVATED gate value: i,f,o -> sigmoid ; g -> tanh
      float act = (tid >= 2 * TH && tid < 3 * TH) ? ftanh(z) : fsig(z);
      zs[tid] = act;
    }
    __syncthreads();   // B2: activated gates ready

    if (tid < TH) {
      float ai = zs[tid];
      float af = zs[tid + TH];
      float ag = zs[tid + 2 * TH];
      float ao = zs[tid + 3 * TH];
      c_reg = af * c_reg + ai * ag;
      float hn = ao * ftanh(c_reg);
      h_s[tid] = hn;
      hout[(size_t)t * TH + tid] = hn;
    }
    __syncthreads();   // B1: h_s visible; zs consumed
    g_cur = g_next;
  }
}

// ---------------------------------------------------------------------------
// Kernel D: out[b,t] = sigmoid( h_seq[b,t] . WoT[qi[b,t]] + bo[qi] )
// ---------------------------------------------------------------------------
__global__ void k_out(const float* __restrict__ h_seq, const float* __restrict__ WoT,
                      const float* __restrict__ bo, const int* __restrict__ qi,
                      float* __restrict__ out) {
  int gid  = blockIdx.x * blockDim.x + threadIdx.x;
  int wave = gid >> 6;
  int lane = threadIdx.x & 63;
  if (wave >= BT) return;
  int s = qi[wave];
  const float4* h4 = (const float4*)(h_seq + (size_t)wave * TH);
  const float4* w4 = (const float4*)(WoT + (size_t)s * TH);
  float acc = 0.0f;
  if (lane < TH / 4) {
    float4 h = h4[lane];
    float4 w = w4[lane];
    acc = h.x * w.x + h.y * w.y + h.z * w.z + h.w * w.w;
  }
  #pragma unroll
  for (int off = 32; off; off >>= 1) acc += __shfl_xor(acc, off);
  if (lane == 0) out[wave] = fsig(acc + bo[s]);
}

// ---------------------------------------------------------------------------
extern "C" void kernel_launch(void* const* d_in, const int* in_sizes, int n_in,
                              void* d_out, int out_size, void* d_ws, size_t ws_size,
                              hipStream_t stream) {
  const float* x    = (const float*)d_in[0];
  // d_in[1] = delta (unused by the reference)
  const float* q    = (const float*)d_in[2];
  const float* Wx   = (const float*)d_in[3];
  const float* bx   = (const float*)d_in[4];
  const float* K    = (const float*)d_in[5];   // lstm_k (103,400)
  const float* R    = (const float*)d_in[6];   // lstm_rk (100,400)
  const float* lb   = (const float*)d_in[7];   // lstm_b (400)
  const float* Wo   = (const float*)d_in[8];   // (100,200)
  const float* bo   = (const float*)d_in[9];   // (200)
  float* out = (float*)d_out;

  // workspace layout (floats)
  float* ws = (float*)d_ws;
  float*  G      = ws;                    // 160000
  float*  base   = ws + 160000;           // 400
  float*  crow0  = ws + 160400;           // 400
  float*  crow1  = ws + 160800;           // 400
  float*  WoT    = ws + 161200;           // 20000
  float*  Rt     = ws + 181200;           // 40000
  int*    idx2   = (int*)(ws + 221200);   // 64000
  int*    qi     = (int*)(ws + 285200);   // 64000
  float*  h_seq  = ws + 349200;           // 6,400,000
  // total: 6,749,200 floats = 27.0 MB

  // A: compress one-hots
  k_compress<<<BT / 4, 256, 0, stream>>>(x, q, idx2, qi);

  // B: precompute tables (G, base, count rows, WoT, Rt)
  int tail_blocks = (TS * TH + NG * TH + 511) / 512;     // 118
  k_precompute<<<NCLS + 1 + tail_blocks, 512, 0, stream>>>(Wx, bx, K, lb, Wo, R,
                                                           G, base, crow0, crow1, WoT, Rt);

  // C: sequential LSTM, one block per batch element (counts ride wave 7)
  k_lstm<<<TB, 512, 0, stream>>>(idx2, G, base, crow0, crow1, Rt, h_seq);

  // D: gather + dot + sigmoid
  k_out<<<BT / 4, 256, 0, stream>>>(h_seq, WoT, bo, qi, out);
}

// Round 5
// 491.078 us; speedup vs baseline: 1.0703x; 1.0703x over previous
//
#include <hip/hip_runtime.h>
#include <hip/hip_bf16.h>
#include <hip/hip_fp16.h>

// Problem constants
#define TB 128
#define TT 500
#define TS 200
#define TE 100
#define TH 100
#define NCLS 400              // 2*S  (one-hot width of x)
#define NG   400              // 4*H  (gate width)
#define BT   (TB*TT)          // 64000 (b,t) pairs
#define BLK  832              // 13 waves; 800 active dot threads

typedef _Float16 h2_t __attribute__((ext_vector_type(2)));
union U16 { float4 f4; h2_t h[4]; };

__device__ __forceinline__ float fsig(float x) { return 1.0f / (1.0f + __expf(-x)); }
__device__ __forceinline__ float ftanh(float x) { float e = __expf(2.0f * x); return 1.0f - 2.0f / (e + 1.0f); }

__device__ __forceinline__ float FDOT2(h2_t a, h2_t b, float c) {
#if __has_builtin(__builtin_amdgcn_fdot2)
  return __builtin_amdgcn_fdot2(a, b, c, false);
#else
  return c + (float)a.x * (float)b.x + (float)a.y * (float)b.y;
#endif
}

// ---------------------------------------------------------------------------
// Kernel A: compress one-hot x (B,T,400) -> idx2 and q (B,T,200) -> qi.
// One wave per (b,t).
// ---------------------------------------------------------------------------
__global__ void k_compress(const float* __restrict__ x, const float* __restrict__ q,
                           int* __restrict__ idx2, int* __restrict__ qi) {
  int gid  = blockIdx.x * blockDim.x + threadIdx.x;
  int wave = gid >> 6;
  int lane = threadIdx.x & 63;
  if (wave >= BT) return;

  const float4* xr = (const float4*)(x + (size_t)wave * NCLS);
  int li = -1;
  {
    float4 v = xr[lane];
    if (v.x > 0.5f) li = lane * 4 + 0;
    if (v.y > 0.5f) li = lane * 4 + 1;
    if (v.z > 0.5f) li = lane * 4 + 2;
    if (v.w > 0.5f) li = lane * 4 + 3;
    int ci = 64 + lane;
    if (ci < 100) {
      float4 w = xr[ci];
      if (w.x > 0.5f) li = ci * 4 + 0;
      if (w.y > 0.5f) li = ci * 4 + 1;
      if (w.z > 0.5f) li = ci * 4 + 2;
      if (w.w > 0.5f) li = ci * 4 + 3;
    }
  }
  #pragma unroll
  for (int off = 32; off; off >>= 1) li = max(li, __shfl_xor(li, off));

  const float4* qr = (const float4*)(q + (size_t)wave * TS);
  int qj = -1;
  if (lane < 50) {
    float4 v = qr[lane];
    if (v.x > 0.5f) qj = lane * 4 + 0;
    if (v.y > 0.5f) qj = lane * 4 + 1;
    if (v.z > 0.5f) qj = lane * 4 + 2;
    if (v.w > 0.5f) qj = lane * 4 + 3;
  }
  #pragma unroll
  for (int off = 32; off; off >>= 1) qj = max(qj, __shfl_xor(qj, off));

  if (lane == 0) { idx2[wave] = li; qi[wave] = qj; }
}

// ---------------------------------------------------------------------------
// Kernel B: precompute G, base, count rows, Wo^T, and packed-f16 R columns.
// Rh2[j*56 + m] = half2( R[2m][j], R[2m+1][j] ), zero-padded for k >= 100.
// Column stride = 56 half2 = 112 halves = 224 B (14 float4).
// ---------------------------------------------------------------------------
__global__ void k_precompute(const float* __restrict__ Wx, const float* __restrict__ bx,
                             const float* __restrict__ K, const float* __restrict__ lb,
                             const float* __restrict__ Wo, const float* __restrict__ R,
                             float* __restrict__ G, float* __restrict__ base,
                             float* __restrict__ crow0, float* __restrict__ crow1,
                             float* __restrict__ WoT, __half2* __restrict__ Rh2) {
  int bid = blockIdx.x, tid = threadIdx.x;
  if (bid < NCLS) {
    if (tid < NG) {
      float acc = 0.0f;
      for (int e = 0; e < TE; ++e) acc = fmaf(Wx[bid * TE + e], K[e * NG + tid], acc);
      G[bid * NG + tid] = acc;
    }
  } else if (bid == NCLS) {
    if (tid < NG) {
      float acc = lb[tid];
      for (int e = 0; e < TE; ++e) acc = fmaf(bx[e], K[e * NG + tid], acc);
      base[tid]  = acc;
      crow0[tid] = K[100 * NG + tid] + K[102 * NG + tid];
      crow1[tid] = K[101 * NG + tid] + K[102 * NG + tid];
    }
  } else {
    int id = (bid - NCLS - 1) * 512 + tid;
    if (id < TS * TH) {
      int s = id / TH, k = id % TH;
      WoT[id] = Wo[k * TS + s];
    } else {
      int id2 = id - TS * TH;
      if (id2 < NG * 56) {
        int j = id2 / 56, m = id2 % 56;
        int k0 = 2 * m, k1 = 2 * m + 1;
        float a = (k0 < TH) ? R[k0 * NG + j] : 0.0f;
        float b = (k1 < TH) ? R[k1 * NG + j] : 0.0f;
        Rh2[id2] = __halves2half2(__float2half_rn(a), __float2half_rn(b));
      }
    }
  }
}

// ---------------------------------------------------------------------------
// Kernel C: LSTM recurrence. One block per batch b, 832 threads (13 waves).
// 2 threads per gate-column: thread t<400 owns column j=t, halves k 0..55;
// thread 400..799 owns column j=t-400, halves k 56..111 (zero-padded).
// Each holds 7 float4 (28 VGPRs) of packed-f16 weights, asm-pinned —
// total VGPR ask ~55, under the allocator's max-occupancy budget, so the
// fragment cannot profitably spill (rounds 2-4 showed a 100-reg f32
// fragment always spilled to scratch and was L2-BW-bound at ~26 TB/s).
// h is packed f16 in LDS (broadcast float4 reads); dot via v_dot2_f32_f16
// (f32 accumulate). Thread 831 runs the count scan 2 steps ahead.
// ---------------------------------------------------------------------------
#define OPQ4(v) asm("" : "+v"(v.x), "+v"(v.y), "+v"(v.z), "+v"(v.w))

__global__ void __launch_bounds__(BLK) k_lstm(const int* __restrict__ idx2,
                                              const float* __restrict__ G,
                                              const float* __restrict__ base,
                                              const float* __restrict__ crow0,
                                              const float* __restrict__ crow1,
                                              const __half2* __restrict__ Rh2,
                                              float* __restrict__ h_seq) {
  int b = blockIdx.x;
  int tid = threadIdx.x;

  __shared__ __align__(16) __half h_h[112];   // packed h (f16), zero-padded
  __shared__ float zs[NG];                    // activated gates
  __shared__ float pz[NG];                    // half-1 partial sums
  __shared__ float cnt[NCLS];
  __shared__ float base_ls[NG], c0_ls[NG], c1_ls[NG];
  __shared__ float2 ccic_ls[4];
  __shared__ int idx_ls[TT];

  for (int i = tid; i < TT; i += BLK) idx_ls[i] = idx2[(size_t)b * TT + i];
  for (int i = tid; i < NCLS; i += BLK) {
    cnt[i] = 0.0f;
    base_ls[i] = base[i]; c0_ls[i] = crow0[i]; c1_ls[i] = crow1[i];
  }
  if (tid < 112) h_h[tid] = __float2half(0.0f);
  float c_reg = 0.0f;

  // weight fragment: 7 float4 = 28 half2 = 56 halves
  int j  = (tid < NG) ? tid : ((tid < 2 * NG) ? tid - NG : 0);
  int hf = (tid >= NG && tid < 2 * NG) ? 1 : 0;
  const float4* rp = (const float4*)Rh2;   // 14 float4 per column
  int cb = j * 14 + hf * 7;
  float4 w0 = rp[cb + 0], w1 = rp[cb + 1], w2 = rp[cb + 2], w3 = rp[cb + 3];
  float4 w4 = rp[cb + 4], w5 = rp[cb + 5], w6 = rp[cb + 6];
  OPQ4(w0); OPQ4(w1); OPQ4(w2); OPQ4(w3); OPQ4(w4); OPQ4(w5); OPQ4(w6);

  __syncthreads();               // idx_ls, cnt, h_h, consts visible

  if (tid == 831) {              // seed count features for t = 0, 1
    #pragma unroll
    for (int tt = 0; tt < 2; ++tt) {
      int cls = idx_ls[tt];
      float n = cnt[cls] + 1.0f; cnt[cls] = n;
      float ns = cnt[cls ^ 1];
      float va = (cls & 1) ? ns : n;
      float vb = (cls & 1) ? n : ns;
      ccic_ls[tt] = make_float2(__logf(1.0f + va), __logf(1.0f + vb));
    }
  }
  float g_cur = (tid < NG) ? G[(size_t)idx_ls[0] * NG + tid] : 0.0f;
  __syncthreads();               // ccic_ls[0..1] visible

  float* hout = h_seq + (size_t)b * TT * TH;

  for (int t = 0; t < TT; ++t) {
    // prefetch next step's G row (lands during this step's work)
    int tn1 = (t + 1 < TT) ? t + 1 : t;
    float g_next = (tid < NG) ? G[(size_t)idx_ls[tn1] * NG + tid] : 0.0f;

    // count scan, 2 steps ahead (off the critical path)
    if (tid == 831) {
      int tn = t + 2;
      if (tn < TT) {
        int cls = idx_ls[tn];
        float n = cnt[cls] + 1.0f; cnt[cls] = n;
        float ns = cnt[cls ^ 1];
        float va = (cls & 1) ? ns : n;
        float vb = (cls & 1) ? n : ns;
        ccic_ls[tn & 3] = make_float2(__logf(1.0f + va), __logf(1.0f + vb));
      }
    }

    // Phase W: 800 threads, 28 fdot2 each (half a column)
    float a0 = 0.0f, a1 = 0.0f;
    if (tid < 2 * NG) {
      const float4* hp = (const float4*)h_h;
      int hb = hf * 7;
      #define DOTC(c, wr) { U16 uh, uw; uh.f4 = hp[hb + c]; uw.f4 = wr; \
        a0 = FDOT2(uh.h[0], uw.h[0], a0); a1 = FDOT2(uh.h[1], uw.h[1], a1); \
        a0 = FDOT2(uh.h[2], uw.h[2], a0); a1 = FDOT2(uh.h[3], uw.h[3], a1); }
      DOTC(0, w0) DOTC(1, w1) DOTC(2, w2) DOTC(3, w3)
      DOTC(4, w4) DOTC(5, w5) DOTC(6, w6)
      #undef DOTC
      if (tid >= NG) pz[j] = a0 + a1;
    }
    __syncthreads();   // B2: pz ready (and prev-step zs fully consumed)

    // Phase A: 400 threads, combine partials + activation
    if (tid < NG) {
      float2 cc = ccic_ls[t & 3];
      float z = base_ls[tid] + cc.x * c0_ls[tid] + cc.y * c1_ls[tid]
              + g_cur + (a0 + a1) + pz[tid];
      zs[tid] = (tid >= 2 * TH && tid < 3 * TH) ? ftanh(z) : fsig(z);
    }
    __syncthreads();   // B3: activated gates ready

    // Phase H: 100 threads, state update
    if (tid < TH) {
      float ai = zs[tid];
      float af = zs[tid + TH];
      float ag = zs[tid + 2 * TH];
      float ao = zs[tid + 3 * TH];
      c_reg = af * c_reg + ai * ag;
      float hn = ao * ftanh(c_reg);
      h_h[tid] = __float2half_rn(hn);
      hout[(size_t)t * TH + tid] = hn;
    }
    __syncthreads();   // B1: h_h ready for next W; zs/pz reusable
    g_cur = g_next;
  }
}

// ---------------------------------------------------------------------------
// Kernel D: out[b,t] = sigmoid( h_seq[b,t] . WoT[qi[b,t]] + bo[qi] )
// ---------------------------------------------------------------------------
__global__ void k_out(const float* __restrict__ h_seq, const float* __restrict__ WoT,
                      const float* __restrict__ bo, const int* __restrict__ qi,
                      float* __restrict__ out) {
  int gid  = blockIdx.x * blockDim.x + threadIdx.x;
  int wave = gid >> 6;
  int lane = threadIdx.x & 63;
  if (wave >= BT) return;
  int s = qi[wave];
  const float4* h4 = (const float4*)(h_seq + (size_t)wave * TH);
  const float4* w4 = (const float4*)(WoT + (size_t)s * TH);
  float acc = 0.0f;
  if (lane < TH / 4) {
    float4 h = h4[lane];
    float4 w = w4[lane];
    acc = h.x * w.x + h.y * w.y + h.z * w.z + h.w * w.w;
  }
  #pragma unroll
  for (int off = 32; off; off >>= 1) acc += __shfl_xor(acc, off);
  if (lane == 0) out[wave] = fsig(acc + bo[s]);
}

// ---------------------------------------------------------------------------
extern "C" void kernel_launch(void* const* d_in, const int* in_sizes, int n_in,
                              void* d_out, int out_size, void* d_ws, size_t ws_size,
                              hipStream_t stream) {
  const float* x    = (const float*)d_in[0];
  // d_in[1] = delta (unused by the reference)
  const float* q    = (const float*)d_in[2];
  const float* Wx   = (const float*)d_in[3];
  const float* bx   = (const float*)d_in[4];
  const float* K    = (const float*)d_in[5];   // lstm_k (103,400)
  const float* R    = (const float*)d_in[6];   // lstm_rk (100,400)
  const float* lb   = (const float*)d_in[7];   // lstm_b (400)
  const float* Wo   = (const float*)d_in[8];   // (100,200)
  const float* bo   = (const float*)d_in[9];   // (200)
  float* out = (float*)d_out;

  // workspace layout (floats)
  float* ws = (float*)d_ws;
  float*   G      = ws;                    // 160000
  float*   base   = ws + 160000;           // 400
  float*   crow0  = ws + 160400;           // 400
  float*   crow1  = ws + 160800;           // 400
  float*   WoT    = ws + 161200;           // 20000
  __half2* Rh2    = (__half2*)(ws + 181200); // 22400 half2 = 22400 floats
  int*     idx2   = (int*)(ws + 203600);   // 64000
  int*     qi     = (int*)(ws + 267600);   // 64000
  float*   h_seq  = ws + 331600;           // 6,400,000
  // total: 6,731,600 floats = 26.9 MB

  // A: compress one-hots
  k_compress<<<BT / 4, 256, 0, stream>>>(x, q, idx2, qi);

  // B: precompute tables (G, base, count rows, WoT, packed-f16 R)
  int tail_blocks = (TS * TH + NG * 56 + 511) / 512;     // 83
  k_precompute<<<NCLS + 1 + tail_blocks, 512, 0, stream>>>(Wx, bx, K, lb, Wo, R,
                                                           G, base, crow0, crow1, WoT, Rh2);

  // C: sequential LSTM, one block per batch element
  k_lstm<<<TB, BLK, 0, stream>>>(idx2, G, base, crow0, crow1, Rh2, h_seq);

  // D: gather + dot + sigmoid
  k_out<<<BT / 4, 256, 0, stream>>>(h_seq, WoT, bo, qi, out);
}